// Round 3
// baseline (428.929 us; speedup 1.0000x reference)
//
#include <hip/hip_runtime.h>

// Problem constants (from reference setup_inputs)
#define B_SAMPLES 50000
#define F_FEATS   100
#define T_TREES   2000
#define N_INTERNAL 63
#define N_LEAVES  64
#define DEPTH     6
#define N_CLASSES 10
#define LR        0.1f

#define BLK 128                       // samples (threads) per block
#define TREES_PER_GROUP 40            // concurrent traversals per thread (ILP)
#define NCHUNK 10                     // tree chunks (grid multiplier)
#define TREES_PER_CHUNK (T_TREES / NCHUNK)              // 200
#define GROUPS_PER_CHUNK (TREES_PER_CHUNK / TREES_PER_GROUP)  // 5
#define NODE_STRIDE 64                // padded per-tree node stride (8B nodes)
#define NSB ((B_SAMPLES + BLK - 1) / BLK)               // 391 sample-blocks

// ---- pre-pass: pack (feature, threshold) into int2 nodes[t*64 + i] ----
__global__ __launch_bounds__(256) void pack_nodes_kernel(
    const float* __restrict__ thresholds,
    const int*   __restrict__ features,
    int2*        __restrict__ nodes)
{
    int e = blockIdx.x * 256 + threadIdx.x;
    if (e < T_TREES * N_INTERNAL) {
        int t = e / N_INTERNAL;
        int i = e - t * N_INTERNAL;
        nodes[t * NODE_STRIDE + i] = make_int2(features[e], __float_as_int(thresholds[e]));
    }
}

// ---- main kernel: thread = sample, block = (sample-block, tree-chunk) ----
// __launch_bounds__(128, 2): cap VGPRs at 256 so 40 node loads can stay in
// flight; occupancy is LDS-capped at 3 blocks/CU (51.2 KB each) regardless.
template<bool PARTIALS>
__global__ __launch_bounds__(BLK, 2) void forest_kernel(
    const float* __restrict__ x,
    const int2*  __restrict__ nodes,
    const float* __restrict__ leaves,
    float*       __restrict__ accum)   // PARTIALS: [NCHUNK][B][10]; else [B][10] (atomic)
{
    __shared__ float xs[F_FEATS * BLK];   // xs[f*BLK + tid] : bank = tid%32, conflict-free
    const int tid   = threadIdx.x;
    const int chunk = blockIdx.x % NCHUNK;          // adjacent blocks share x slab (L2-hot)
    const int sb    = blockIdx.x / NCHUNK;
    const int b     = sb * BLK + tid;
    const bool valid = (b < B_SAMPLES);

    // stage this sample's feature row into LDS (transposed)
    {
        const float4* xrow = reinterpret_cast<const float4*>(x + (size_t)b * F_FEATS);
        #pragma unroll
        for (int k = 0; k < F_FEATS / 4; ++k) {
            float4 v = valid ? xrow[k] : make_float4(0.f, 0.f, 0.f, 0.f);
            xs[(4 * k + 0) * BLK + tid] = v.x;
            xs[(4 * k + 1) * BLK + tid] = v.y;
            xs[(4 * k + 2) * BLK + tid] = v.z;
            xs[(4 * k + 3) * BLK + tid] = v.w;
        }
    }
    __syncthreads();

    float acc[N_CLASSES];
    #pragma unroll
    for (int c = 0; c < N_CLASSES; ++c) acc[c] = 0.f;

    const int2*  cnodes  = nodes  + (size_t)chunk * TREES_PER_CHUNK * NODE_STRIDE;
    const float* cleaves = leaves + (size_t)chunk * TREES_PER_CHUNK * N_LEAVES;

    for (int g = 0; g < GROUPS_PER_CHUNK; ++g) {
        const int2*  nbase = cnodes  + (size_t)g * TREES_PER_GROUP * NODE_STRIDE;
        const float* lbase = cleaves + (size_t)g * TREES_PER_GROUP * N_LEAVES;

        int idx[TREES_PER_GROUP];
        #pragma unroll
        for (int j = 0; j < TREES_PER_GROUP; ++j) idx[j] = 0;

        #pragma unroll
        for (int lvl = 0; lvl < DEPTH; ++lvl) {
            int2 nd[TREES_PER_GROUP];
            // issue all 40 node loads (independent; L1/L2-resident)
            #pragma unroll
            for (int j = 0; j < TREES_PER_GROUP; ++j)
                nd[j] = nbase[j * NODE_STRIDE + idx[j]];
            // gather x from LDS, compare, descend
            #pragma unroll
            for (int j = 0; j < TREES_PER_GROUP; ++j) {
                float xv  = xs[nd[j].x * BLK + tid];
                float thr = __int_as_float(nd[j].y);
                idx[j] = 2 * idx[j] + 1 + (xv > thr ? 1 : 0);
            }
        }
        // class of tree (chunk*200 + g*40 + j) is j%10 (200, 40 ≡ 0 mod 10)
        #pragma unroll
        for (int j = 0; j < TREES_PER_GROUP; ++j) {
            float lv = lbase[j * N_LEAVES + (idx[j] - (N_LEAVES - 1))];
            acc[j % N_CLASSES] += lv;
        }
    }

    if (valid) {
        if (PARTIALS) {
            float2* p = reinterpret_cast<float2*>(
                accum + ((size_t)chunk * B_SAMPLES + b) * N_CLASSES);
            #pragma unroll
            for (int c = 0; c < N_CLASSES / 2; ++c)
                p[c] = make_float2(acc[2 * c], acc[2 * c + 1]);
        } else {
            #pragma unroll
            for (int c = 0; c < N_CLASSES; ++c)
                atomicAdd(&accum[(size_t)b * N_CLASSES + c], acc[c]);
        }
    }
}

// ---- epilogue: sum partials, LR scale, log_softmax ----
template<bool PARTIALS>
__global__ __launch_bounds__(256) void softmax_kernel(
    const float* __restrict__ accum,
    float*       __restrict__ out)
{
    int b = blockIdx.x * 256 + threadIdx.x;
    if (b >= B_SAMPLES) return;

    float d[N_CLASSES];
    #pragma unroll
    for (int c = 0; c < N_CLASSES; ++c) d[c] = 0.f;

    if (PARTIALS) {
        for (int ch = 0; ch < NCHUNK; ++ch) {
            const float2* p = reinterpret_cast<const float2*>(
                accum + ((size_t)ch * B_SAMPLES + b) * N_CLASSES);
            #pragma unroll
            for (int c = 0; c < N_CLASSES / 2; ++c) {
                float2 v = p[c];
                d[2 * c]     += v.x;
                d[2 * c + 1] += v.y;
            }
        }
    } else {
        #pragma unroll
        for (int c = 0; c < N_CLASSES; ++c)
            d[c] = accum[(size_t)b * N_CLASSES + c];
    }

    #pragma unroll
    for (int c = 0; c < N_CLASSES; ++c) d[c] *= LR;
    float m = d[0];
    #pragma unroll
    for (int c = 1; c < N_CLASSES; ++c) m = fmaxf(m, d[c]);
    float ssum = 0.f;
    #pragma unroll
    for (int c = 0; c < N_CLASSES; ++c) ssum += expf(d[c] - m);
    float lse = logf(ssum);

    float2* o = reinterpret_cast<float2*>(out + (size_t)b * N_CLASSES);
    #pragma unroll
    for (int c = 0; c < N_CLASSES / 2; ++c)
        o[c] = make_float2(d[2 * c] - m - lse, d[2 * c + 1] - m - lse);
}

extern "C" void kernel_launch(void* const* d_in, const int* in_sizes, int n_in,
                              void* d_out, int out_size, void* d_ws, size_t ws_size,
                              hipStream_t stream) {
    const float* x          = (const float*)d_in[0];   // [50000,100] f32
    const float* thresholds = (const float*)d_in[1];   // [2000,63]  f32
    const float* leaves     = (const float*)d_in[2];   // [2000,64]  f32
    const int*   features   = (const int*)d_in[3];     // [2000,63]  i32
    // d_in[4] = classes (int64 arange, unused)

    const size_t nodes_bytes    = (size_t)T_TREES * NODE_STRIDE * sizeof(int2);       // 1.0 MB
    const size_t partials_bytes = (size_t)NCHUNK * B_SAMPLES * N_CLASSES * sizeof(float); // 20 MB
    const size_t accum_bytes    = (size_t)B_SAMPLES * N_CLASSES * sizeof(float);      // 2 MB

    int2*  nodes  = (int2*)d_ws;
    float* accbuf = (float*)((char*)d_ws + nodes_bytes);
    const bool use_partials = (ws_size >= nodes_bytes + partials_bytes);

    {
        int total = T_TREES * N_INTERNAL;
        pack_nodes_kernel<<<(total + 255) / 256, 256, 0, stream>>>(thresholds, features, nodes);
    }

    if (use_partials) {
        forest_kernel<true><<<NSB * NCHUNK, BLK, 0, stream>>>(x, nodes, leaves, accbuf);
        softmax_kernel<true><<<(B_SAMPLES + 255) / 256, 256, 0, stream>>>(accbuf, (float*)d_out);
    } else {
        hipMemsetAsync(accbuf, 0, accum_bytes, stream);
        forest_kernel<false><<<NSB * NCHUNK, BLK, 0, stream>>>(x, nodes, leaves, accbuf);
        softmax_kernel<false><<<(B_SAMPLES + 255) / 256, 256, 0, stream>>>(accbuf, (float*)d_out);
    }
}

// Round 4
// 411.235 us; speedup vs baseline: 1.0430x; 1.0430x over previous
//
#include <hip/hip_runtime.h>

// Problem constants (from reference setup_inputs)
#define B_SAMPLES 50000
#define F_FEATS   100
#define T_TREES   2000
#define N_INTERNAL 63
#define N_LEAVES  64
#define DEPTH     6
#define N_CLASSES 10
#define LR        0.1f

#define BLK 128                       // samples (threads) per block
#define TPG 20                        // concurrent trees per thread (ILP)
#define NCHUNK 10                     // tree chunks (grid multiplier)
#define TREES_PER_CHUNK (T_TREES / NCHUNK)       // 200
#define GROUPS_PER_CHUNK (TREES_PER_CHUNK / TPG) // 10
#define CP_STRIDE 32                  // int4 slots per tree (31 pairs + root in 31)
#define NSB ((B_SAMPLES + BLK - 1) / BLK)        // 391 sample-blocks

// ---- pre-pass: child-pair node layout ----
// cpairs[t][i] (i<31)  = {f(2i+1), thr(2i+1), f(2i+2), thr(2i+2)}
// cpairs[t][31].xy     = {f(0), thr(0)}   (root)
__global__ __launch_bounds__(256) void pack_nodes_kernel(
    const float* __restrict__ thresholds,
    const int*   __restrict__ features,
    int4*        __restrict__ cpairs)
{
    int e = blockIdx.x * 256 + threadIdx.x;
    int t = e >> 5, i = e & 31;
    if (t < T_TREES) {
        int4 v;
        if (i < 31) {
            int a = t * N_INTERNAL + 2 * i + 1;
            v = make_int4(features[a],     __float_as_int(thresholds[a]),
                          features[a + 1], __float_as_int(thresholds[a + 1]));
        } else {
            int r = t * N_INTERNAL;
            v = make_int4(features[r], __float_as_int(thresholds[r]), 0, 0);
        }
        cpairs[t * CP_STRIDE + i] = v;
    }
}

#define I2F __int_as_float
#define XS(f) xs[((f) << 7) + tid]    // BLK==128: bank = tid%32, conflict-free

// ---- main kernel: thread = sample; fully speculative dual-child traversal ----
template<bool PARTIALS>
__global__ __launch_bounds__(BLK, 1) void forest_kernel(
    const float* __restrict__ x,
    const int4*  __restrict__ cpairs,
    const float* __restrict__ leaves,
    float*       __restrict__ accum)   // PARTIALS: [NCHUNK][B][10]; else [B][10] (atomic)
{
    __shared__ float xs[F_FEATS * BLK];
    const int tid   = threadIdx.x;
    const int chunk = blockIdx.x % NCHUNK;       // adjacent blocks share x slab (L2-hot)
    const int sb    = blockIdx.x / NCHUNK;
    const int b     = sb * BLK + tid;
    const bool valid = (b < B_SAMPLES);

    // stage this sample's feature row into LDS (transposed)
    {
        const float4* xrow = reinterpret_cast<const float4*>(x + (size_t)b * F_FEATS);
        #pragma unroll
        for (int k = 0; k < F_FEATS / 4; ++k) {
            float4 v = valid ? xrow[k] : make_float4(0.f, 0.f, 0.f, 0.f);
            xs[(4 * k + 0) * BLK + tid] = v.x;
            xs[(4 * k + 1) * BLK + tid] = v.y;
            xs[(4 * k + 2) * BLK + tid] = v.z;
            xs[(4 * k + 3) * BLK + tid] = v.w;
        }
    }
    __syncthreads();

    float acc[N_CLASSES];
    #pragma unroll
    for (int c = 0; c < N_CLASSES; ++c) acc[c] = 0.f;

    const int4*  ccp = cpairs + (size_t)chunk * TREES_PER_CHUNK * CP_STRIDE;
    const float* clv = leaves + (size_t)chunk * TREES_PER_CHUNK * N_LEAVES;

    #pragma unroll 1
    for (int g = 0; g < GROUPS_PER_CHUNK; ++g) {
        const int4*  cpb = ccp + (size_t)g * TPG * CP_STRIDE;
        const float* lvb = clv + (size_t)g * TPG * N_LEAVES;

        int   idx[TPG];
        float thrL[TPG], thrR[TPG], xvL[TPG], xvR[TPG];
        int4  cpt[TPG];

        // ---- body 0 (root) + prefetch for body 1 ----
        int2  rt[TPG]; float xv0[TPG];
        #pragma unroll
        for (int j = 0; j < TPG; ++j) {
            rt[j] = *reinterpret_cast<const int2*>(cpb + j * CP_STRIDE + 31);
        }
        #pragma unroll
        for (int j = 0; j < TPG; ++j) cpt[j] = cpb[j * CP_STRIDE + 0];   // level-1 candidates
        #pragma unroll
        for (int j = 0; j < TPG; ++j) xv0[j] = XS(rt[j].x);
        #pragma unroll
        for (int j = 0; j < TPG; ++j) {
            int c = xv0[j] > I2F(rt[j].y);
            idx[j] = 1 + c;                      // level-1 node
        }
        #pragma unroll
        for (int j = 0; j < TPG; ++j) {          // extract level-1 candidates
            thrL[j] = I2F(cpt[j].y); thrR[j] = I2F(cpt[j].w);
            xvL[j]  = XS(cpt[j].x);  xvR[j]  = XS(cpt[j].z);
        }
        #pragma unroll
        for (int j = 0; j < TPG; ++j) cpt[j] = cpb[j * CP_STRIDE + idx[j]]; // cpair[idx1]

        float2 lf[TPG];

        // ---- bodies 1..4 ----
        #pragma unroll
        for (int lvl = 1; lvl <= 4; ++lvl) {
            #pragma unroll
            for (int j = 0; j < TPG; ++j) {
                bool odd  = (idx[j] & 1);        // odd => left child was chosen
                float thr = odd ? thrL[j] : thrR[j];
                float xv  = odd ? xvL[j]  : xvR[j];
                int c = xv > thr;
                idx[j] = 2 * idx[j] + 1 + c;     // level lvl+1 node
            }
            if (lvl < 4) {
                #pragma unroll
                for (int j = 0; j < TPG; ++j) {  // cpt = cpair[idx_lvl]: level lvl+1 candidates
                    thrL[j] = I2F(cpt[j].y); thrR[j] = I2F(cpt[j].w);
                    xvL[j]  = XS(cpt[j].x);  xvR[j]  = XS(cpt[j].z);
                }
                #pragma unroll
                for (int j = 0; j < TPG; ++j) cpt[j] = cpb[j * CP_STRIDE + idx[j]];
            } else {
                #pragma unroll
                for (int j = 0; j < TPG; ++j) {  // level-5 candidates
                    thrL[j] = I2F(cpt[j].y); thrR[j] = I2F(cpt[j].w);
                    xvL[j]  = XS(cpt[j].x);  xvR[j]  = XS(cpt[j].z);
                }
                #pragma unroll
                for (int j = 0; j < TPG; ++j) {  // speculative leaf pair (children of idx5)
                    lf[j] = *reinterpret_cast<const float2*>(
                        lvb + j * N_LEAVES + (2 * idx[j] - 62));
                }
            }
        }

        // ---- body 5 + accumulate ----
        #pragma unroll
        for (int j = 0; j < TPG; ++j) {
            bool odd  = (idx[j] & 1);
            float thr = odd ? thrL[j] : thrR[j];
            float xv  = odd ? xvL[j]  : xvR[j];
            bool c = xv > thr;
            acc[j % N_CLASSES] += c ? lf[j].y : lf[j].x;
        }
    }

    if (valid) {
        if (PARTIALS) {
            float2* p = reinterpret_cast<float2*>(
                accum + ((size_t)chunk * B_SAMPLES + b) * N_CLASSES);
            #pragma unroll
            for (int c = 0; c < N_CLASSES / 2; ++c)
                p[c] = make_float2(acc[2 * c], acc[2 * c + 1]);
        } else {
            #pragma unroll
            for (int c = 0; c < N_CLASSES; ++c)
                atomicAdd(&accum[(size_t)b * N_CLASSES + c], acc[c]);
        }
    }
}

// ---- epilogue: sum partials, LR scale, log_softmax ----
template<bool PARTIALS>
__global__ __launch_bounds__(256) void softmax_kernel(
    const float* __restrict__ accum,
    float*       __restrict__ out)
{
    int b = blockIdx.x * 256 + threadIdx.x;
    if (b >= B_SAMPLES) return;

    float d[N_CLASSES];
    #pragma unroll
    for (int c = 0; c < N_CLASSES; ++c) d[c] = 0.f;

    if (PARTIALS) {
        for (int ch = 0; ch < NCHUNK; ++ch) {
            const float2* p = reinterpret_cast<const float2*>(
                accum + ((size_t)ch * B_SAMPLES + b) * N_CLASSES);
            #pragma unroll
            for (int c = 0; c < N_CLASSES / 2; ++c) {
                float2 v = p[c];
                d[2 * c]     += v.x;
                d[2 * c + 1] += v.y;
            }
        }
    } else {
        #pragma unroll
        for (int c = 0; c < N_CLASSES; ++c)
            d[c] = accum[(size_t)b * N_CLASSES + c];
    }

    #pragma unroll
    for (int c = 0; c < N_CLASSES; ++c) d[c] *= LR;
    float m = d[0];
    #pragma unroll
    for (int c = 1; c < N_CLASSES; ++c) m = fmaxf(m, d[c]);
    float ssum = 0.f;
    #pragma unroll
    for (int c = 0; c < N_CLASSES; ++c) ssum += expf(d[c] - m);
    float lse = logf(ssum);

    float2* o = reinterpret_cast<float2*>(out + (size_t)b * N_CLASSES);
    #pragma unroll
    for (int c = 0; c < N_CLASSES / 2; ++c)
        o[c] = make_float2(d[2 * c] - m - lse, d[2 * c + 1] - m - lse);
}

extern "C" void kernel_launch(void* const* d_in, const int* in_sizes, int n_in,
                              void* d_out, int out_size, void* d_ws, size_t ws_size,
                              hipStream_t stream) {
    const float* x          = (const float*)d_in[0];   // [50000,100] f32
    const float* thresholds = (const float*)d_in[1];   // [2000,63]  f32
    const float* leaves     = (const float*)d_in[2];   // [2000,64]  f32
    const int*   features   = (const int*)d_in[3];     // [2000,63]  i32
    // d_in[4] = classes (int64 arange, unused)

    const size_t cpairs_bytes   = (size_t)T_TREES * CP_STRIDE * sizeof(int4);         // 1.0 MB
    const size_t partials_bytes = (size_t)NCHUNK * B_SAMPLES * N_CLASSES * sizeof(float); // 20 MB
    const size_t accum_bytes    = (size_t)B_SAMPLES * N_CLASSES * sizeof(float);      // 2 MB

    int4*  cpairs = (int4*)d_ws;
    float* accbuf = (float*)((char*)d_ws + cpairs_bytes);
    const bool use_partials = (ws_size >= cpairs_bytes + partials_bytes);

    {
        int total = T_TREES * CP_STRIDE;               // 64000
        pack_nodes_kernel<<<(total + 255) / 256, 256, 0, stream>>>(thresholds, features, cpairs);
    }

    if (use_partials) {
        forest_kernel<true><<<NSB * NCHUNK, BLK, 0, stream>>>(x, cpairs, leaves, accbuf);
        softmax_kernel<true><<<(B_SAMPLES + 255) / 256, 256, 0, stream>>>(accbuf, (float*)d_out);
    } else {
        hipMemsetAsync(accbuf, 0, accum_bytes, stream);
        forest_kernel<false><<<NSB * NCHUNK, BLK, 0, stream>>>(x, cpairs, leaves, accbuf);
        softmax_kernel<false><<<(B_SAMPLES + 255) / 256, 256, 0, stream>>>(accbuf, (float*)d_out);
    }
}

// Round 5
// 402.166 us; speedup vs baseline: 1.0665x; 1.0226x over previous
//
#include <hip/hip_runtime.h>

// Problem constants (from reference setup_inputs)
#define B_SAMPLES 50000
#define F_FEATS   100
#define T_TREES   2000
#define N_INTERNAL 63
#define N_LEAVES  64
#define DEPTH     6
#define N_CLASSES 10
#define LR        0.1f

#define BLK 128                       // samples (threads) per block
#define TPG 40                        // concurrent trees per thread (ILP)
#define NCHUNK 10                     // tree chunks (grid multiplier)
#define TREES_PER_CHUNK (T_TREES / NCHUNK)       // 200
#define GROUPS_PER_CHUNK (TREES_PER_CHUNK / TPG) // 5
#define NODE_STRIDE 64                // padded per-tree node stride (8B nodes)
#define NSB ((B_SAMPLES + BLK - 1) / BLK)        // 391 sample-blocks

// ---- pre-pass: pack (feature, threshold) into int2 nodes[t*64 + i] ----
__global__ __launch_bounds__(256) void pack_nodes_kernel(
    const float* __restrict__ thresholds,
    const int*   __restrict__ features,
    int2*        __restrict__ nodes)
{
    int e = blockIdx.x * 256 + threadIdx.x;
    if (e < T_TREES * N_INTERNAL) {
        int t = e / N_INTERNAL;
        int i = e - t * N_INTERNAL;
        nodes[t * NODE_STRIDE + i] = make_int2(features[e], __float_as_int(thresholds[e]));
    }
}

#define I2F __int_as_float
#define XS(f) xs[((f) << 7) + tid]    // BLK==128: bank = tid%32, conflict-free

// ---- main kernel: thread = sample, block = (sample-block, tree-chunk) ----
// __launch_bounds__(BLK, 1): occupancy is LDS-capped (51.2 KB/block -> 3
// blocks/CU) so let the register allocator take what it needs — R3 showed
// this avoids the scratch spill that killed R2's (BLK,2) variant.
template<bool PARTIALS>
__global__ __launch_bounds__(BLK, 1) void forest_kernel(
    const float* __restrict__ x,
    const int2*  __restrict__ nodes,
    const float* __restrict__ leaves,
    float*       __restrict__ accum)   // PARTIALS: [NCHUNK][B][10]; else [B][10] (atomic)
{
    __shared__ float xs[F_FEATS * BLK];
    const int tid   = threadIdx.x;
    const int chunk = blockIdx.x % NCHUNK;       // adjacent blocks share x slab (L2-hot)
    const int sb    = blockIdx.x / NCHUNK;
    const int b     = sb * BLK + tid;
    const bool valid = (b < B_SAMPLES);

    // stage this sample's feature row into LDS (transposed)
    {
        const float4* xrow = reinterpret_cast<const float4*>(x + (size_t)b * F_FEATS);
        #pragma unroll
        for (int k = 0; k < F_FEATS / 4; ++k) {
            float4 v = valid ? xrow[k] : make_float4(0.f, 0.f, 0.f, 0.f);
            xs[(4 * k + 0) * BLK + tid] = v.x;
            xs[(4 * k + 1) * BLK + tid] = v.y;
            xs[(4 * k + 2) * BLK + tid] = v.z;
            xs[(4 * k + 3) * BLK + tid] = v.w;
        }
    }
    __syncthreads();

    float acc[N_CLASSES];
    #pragma unroll
    for (int c = 0; c < N_CLASSES; ++c) acc[c] = 0.f;

    const int2*  cnodes  = nodes  + (size_t)chunk * TREES_PER_CHUNK * NODE_STRIDE;
    const float* cleaves = leaves + (size_t)chunk * TREES_PER_CHUNK * N_LEAVES;

    #pragma unroll 1
    for (int g = 0; g < GROUPS_PER_CHUNK; ++g) {
        const int2*  nbase = cnodes  + (size_t)g * TPG * NODE_STRIDE;
        const float* lbase = cleaves + (size_t)g * TPG * N_LEAVES;

        int idx[TPG];
        #pragma unroll
        for (int j = 0; j < TPG; ++j) idx[j] = 0;

        #pragma unroll
        for (int lvl = 0; lvl < DEPTH; ++lvl) {
            int2 nd[TPG];
            // issue all 40 node loads (independent; L1/L2-resident)
            #pragma unroll
            for (int j = 0; j < TPG; ++j)
                nd[j] = nbase[j * NODE_STRIDE + idx[j]];
            // gather x from LDS, compare, descend (branchless)
            #pragma unroll
            for (int j = 0; j < TPG; ++j) {
                float xv  = XS(nd[j].x);
                float thr = I2F(nd[j].y);
                idx[j] += idx[j] + 1 + (xv > thr ? 1 : 0);
            }
        }
        // class of tree (chunk*200 + g*40 + j) is j%10 (200, 40 ≡ 0 mod 10)
        #pragma unroll
        for (int j = 0; j < TPG; ++j) {
            float lv = lbase[j * N_LEAVES + (idx[j] - (N_LEAVES - 1))];
            acc[j % N_CLASSES] += lv;
        }
    }

    if (valid) {
        if (PARTIALS) {
            float2* p = reinterpret_cast<float2*>(
                accum + ((size_t)chunk * B_SAMPLES + b) * N_CLASSES);
            #pragma unroll
            for (int c = 0; c < N_CLASSES / 2; ++c)
                p[c] = make_float2(acc[2 * c], acc[2 * c + 1]);
        } else {
            #pragma unroll
            for (int c = 0; c < N_CLASSES; ++c)
                atomicAdd(&accum[(size_t)b * N_CLASSES + c], acc[c]);
        }
    }
}

// ---- epilogue: sum partials, LR scale, log_softmax ----
template<bool PARTIALS>
__global__ __launch_bounds__(256) void softmax_kernel(
    const float* __restrict__ accum,
    float*       __restrict__ out)
{
    int b = blockIdx.x * 256 + threadIdx.x;
    if (b >= B_SAMPLES) return;

    float d[N_CLASSES];
    #pragma unroll
    for (int c = 0; c < N_CLASSES; ++c) d[c] = 0.f;

    if (PARTIALS) {
        for (int ch = 0; ch < NCHUNK; ++ch) {
            const float2* p = reinterpret_cast<const float2*>(
                accum + ((size_t)ch * B_SAMPLES + b) * N_CLASSES);
            #pragma unroll
            for (int c = 0; c < N_CLASSES / 2; ++c) {
                float2 v = p[c];
                d[2 * c]     += v.x;
                d[2 * c + 1] += v.y;
            }
        }
    } else {
        #pragma unroll
        for (int c = 0; c < N_CLASSES; ++c)
            d[c] = accum[(size_t)b * N_CLASSES + c];
    }

    #pragma unroll
    for (int c = 0; c < N_CLASSES; ++c) d[c] *= LR;
    float m = d[0];
    #pragma unroll
    for (int c = 1; c < N_CLASSES; ++c) m = fmaxf(m, d[c]);
    float ssum = 0.f;
    #pragma unroll
    for (int c = 0; c < N_CLASSES; ++c) ssum += expf(d[c] - m);
    float lse = logf(ssum);

    float2* o = reinterpret_cast<float2*>(out + (size_t)b * N_CLASSES);
    #pragma unroll
    for (int c = 0; c < N_CLASSES / 2; ++c)
        o[c] = make_float2(d[2 * c] - m - lse, d[2 * c + 1] - m - lse);
}

extern "C" void kernel_launch(void* const* d_in, const int* in_sizes, int n_in,
                              void* d_out, int out_size, void* d_ws, size_t ws_size,
                              hipStream_t stream) {
    const float* x          = (const float*)d_in[0];   // [50000,100] f32
    const float* thresholds = (const float*)d_in[1];   // [2000,63]  f32
    const float* leaves     = (const float*)d_in[2];   // [2000,64]  f32
    const int*   features   = (const int*)d_in[3];     // [2000,63]  i32
    // d_in[4] = classes (int64 arange, unused)

    const size_t nodes_bytes    = (size_t)T_TREES * NODE_STRIDE * sizeof(int2);       // 1.0 MB
    const size_t partials_bytes = (size_t)NCHUNK * B_SAMPLES * N_CLASSES * sizeof(float); // 20 MB
    const size_t accum_bytes    = (size_t)B_SAMPLES * N_CLASSES * sizeof(float);      // 2 MB

    int2*  nodes  = (int2*)d_ws;
    float* accbuf = (float*)((char*)d_ws + nodes_bytes);
    const bool use_partials = (ws_size >= nodes_bytes + partials_bytes);

    {
        int total = T_TREES * N_INTERNAL;
        pack_nodes_kernel<<<(total + 255) / 256, 256, 0, stream>>>(thresholds, features, nodes);
    }

    if (use_partials) {
        forest_kernel<true><<<NSB * NCHUNK, BLK, 0, stream>>>(x, nodes, leaves, accbuf);
        softmax_kernel<true><<<(B_SAMPLES + 255) / 256, 256, 0, stream>>>(accbuf, (float*)d_out);
    } else {
        hipMemsetAsync(accbuf, 0, accum_bytes, stream);
        forest_kernel<false><<<NSB * NCHUNK, BLK, 0, stream>>>(x, nodes, leaves, accbuf);
        softmax_kernel<false><<<(B_SAMPLES + 255) / 256, 256, 0, stream>>>(accbuf, (float*)d_out);
    }
}

// Round 6
// 390.133 us; speedup vs baseline: 1.0994x; 1.0308x over previous
//
#include <hip/hip_runtime.h>

// Problem constants (from reference setup_inputs)
#define B_SAMPLES 50000
#define F_FEATS   100
#define T_TREES   2000
#define N_INTERNAL 63
#define N_LEAVES  64
#define DEPTH     6
#define N_CLASSES 10
#define LR        0.1f

#define BLK 128                       // samples (threads) per block
#define TPG 20                        // concurrent trees per thread
#define QS  5                         // quarter size (4 rotating quarters)
#define NCHUNK 10                     // tree chunks (grid multiplier)
#define TREES_PER_CHUNK (T_TREES / NCHUNK)       // 200
#define GROUPS_PER_CHUNK (TREES_PER_CHUNK / TPG) // 10
#define NODE_STRIDE 64                // padded per-tree node stride (8B nodes)
#define NSB ((B_SAMPLES + BLK - 1) / BLK)        // 391 sample-blocks

// ---- pre-pass: pack (feature, threshold) into int2 nodes[t*64 + i] ----
__global__ __launch_bounds__(256) void pack_nodes_kernel(
    const float* __restrict__ thresholds,
    const int*   __restrict__ features,
    int2*        __restrict__ nodes)
{
    int e = blockIdx.x * 256 + threadIdx.x;
    if (e < T_TREES * N_INTERNAL) {
        int t = e / N_INTERNAL;
        int i = e - t * N_INTERNAL;
        nodes[t * NODE_STRIDE + i] = make_int2(features[e], __float_as_int(thresholds[e]));
    }
}

#define I2F __int_as_float
#define XS(f) xs[((f) << 7) + tid]    // BLK==128: bank = tid%32, conflict-free

// ---- main kernel ----
// thread = sample; 20 trees as 4 quarters of 5 in a 3-stage software pipeline:
//   step s:  S2: issue ds_reads for quarter (s+1)%4  (its gld was 4 steps ago)
//            S3: compare quarter s%4 (xv issued 1 step ago), issue next gld
// chunk = bid/NSB: a CU's temporally-adjacent blocks (bid stride ~256 < 391)
// share the same 102KB node stream -> L1-warm node gathers.
template<bool PARTIALS>
__global__ __launch_bounds__(BLK, 1) void forest_kernel(
    const float* __restrict__ x,
    const int2*  __restrict__ nodes,
    const float* __restrict__ leaves,
    float*       __restrict__ accum)   // PARTIALS: [NCHUNK][B][10]; else [B][10] (atomic)
{
    __shared__ float xs[F_FEATS * BLK];
    const int tid   = threadIdx.x;
    const int chunk = blockIdx.x / NSB;          // chunk-major: co-resident blocks share nodes
    const int sb    = blockIdx.x % NSB;
    const int b     = sb * BLK + tid;
    const bool valid = (b < B_SAMPLES);

    // stage this sample's feature row into LDS (transposed)
    {
        const float4* xrow = reinterpret_cast<const float4*>(x + (size_t)b * F_FEATS);
        #pragma unroll
        for (int k = 0; k < F_FEATS / 4; ++k) {
            float4 v = valid ? xrow[k] : make_float4(0.f, 0.f, 0.f, 0.f);
            xs[(4 * k + 0) * BLK + tid] = v.x;
            xs[(4 * k + 1) * BLK + tid] = v.y;
            xs[(4 * k + 2) * BLK + tid] = v.z;
            xs[(4 * k + 3) * BLK + tid] = v.w;
        }
    }
    __syncthreads();

    float acc[N_CLASSES];
    #pragma unroll
    for (int c = 0; c < N_CLASSES; ++c) acc[c] = 0.f;

    const int2*  cnodes  = nodes  + (size_t)chunk * TREES_PER_CHUNK * NODE_STRIDE;
    const float* cleaves = leaves + (size_t)chunk * TREES_PER_CHUNK * N_LEAVES;

    #pragma unroll 1
    for (int g = 0; g < GROUPS_PER_CHUNK; ++g) {
        const int2*  nb = cnodes  + (size_t)g * TPG * NODE_STRIDE;
        const float* lb = cleaves + (size_t)g * TPG * N_LEAVES;

        int   idx[TPG];
        int2  nd [TPG];
        float xv [TPG];
        float lf [TPG];

        #pragma unroll
        for (int j = 0; j < TPG; ++j) idx[j] = 0;
        // roots: uniform addresses -> scalar loads, issued early
        #pragma unroll
        for (int j = 0; j < TPG; ++j) nd[j] = nb[j * NODE_STRIDE];
        // prologue: ds for quarter 0 @ level 0
        #pragma unroll
        for (int jj = 0; jj < QS; ++jj) xv[jj] = XS(nd[jj].x);

        // 24 steps = 6 levels x 4 quarters (all indices compile-time after unroll)
        #pragma unroll
        for (int s = 0; s < 24; ++s) {
            // S2: issue ds_reads for quarter (s+1)%4 at level (s+1)/4
            {
                const int s1 = s + 1, q2 = s1 & 3, l2 = s1 >> 2, o2 = q2 * QS;
                if (l2 <= 5) {
                    #pragma unroll
                    for (int jj = 0; jj < QS; ++jj) {
                        const int j = o2 + jj;
                        xv[j] = XS(nd[j].x);
                    }
                }
            }
            // S3: finish quarter s%4 at level s/4; issue its next-level gld
            {
                const int q = s & 3, l = s >> 2, o = q * QS;
                #pragma unroll
                for (int jj = 0; jj < QS; ++jj) {
                    const int j = o + jj;
                    idx[j] += idx[j] + 1 + (xv[j] > I2F(nd[j].y) ? 1 : 0);
                    if (l < 5) nd[j] = nb[j * NODE_STRIDE + idx[j]];
                    else       lf[j] = lb[j * N_LEAVES + idx[j] - (N_LEAVES - 1)];
                }
            }
        }

        // epilogue: accumulate leaves (class of tree chunk*200+g*20+j is j%10)
        #pragma unroll
        for (int j = 0; j < TPG; ++j) acc[j % N_CLASSES] += lf[j];
    }

    if (valid) {
        if (PARTIALS) {
            float2* p = reinterpret_cast<float2*>(
                accum + ((size_t)chunk * B_SAMPLES + b) * N_CLASSES);
            #pragma unroll
            for (int c = 0; c < N_CLASSES / 2; ++c)
                p[c] = make_float2(acc[2 * c], acc[2 * c + 1]);
        } else {
            #pragma unroll
            for (int c = 0; c < N_CLASSES; ++c)
                atomicAdd(&accum[(size_t)b * N_CLASSES + c], acc[c]);
        }
    }
}

// ---- epilogue: sum partials, LR scale, log_softmax ----
template<bool PARTIALS>
__global__ __launch_bounds__(256) void softmax_kernel(
    const float* __restrict__ accum,
    float*       __restrict__ out)
{
    int b = blockIdx.x * 256 + threadIdx.x;
    if (b >= B_SAMPLES) return;

    float d[N_CLASSES];
    #pragma unroll
    for (int c = 0; c < N_CLASSES; ++c) d[c] = 0.f;

    if (PARTIALS) {
        for (int ch = 0; ch < NCHUNK; ++ch) {
            const float2* p = reinterpret_cast<const float2*>(
                accum + ((size_t)ch * B_SAMPLES + b) * N_CLASSES);
            #pragma unroll
            for (int c = 0; c < N_CLASSES / 2; ++c) {
                float2 v = p[c];
                d[2 * c]     += v.x;
                d[2 * c + 1] += v.y;
            }
        }
    } else {
        #pragma unroll
        for (int c = 0; c < N_CLASSES; ++c)
            d[c] = accum[(size_t)b * N_CLASSES + c];
    }

    #pragma unroll
    for (int c = 0; c < N_CLASSES; ++c) d[c] *= LR;
    float m = d[0];
    #pragma unroll
    for (int c = 1; c < N_CLASSES; ++c) m = fmaxf(m, d[c]);
    float ssum = 0.f;
    #pragma unroll
    for (int c = 0; c < N_CLASSES; ++c) ssum += expf(d[c] - m);
    float lse = logf(ssum);

    float2* o = reinterpret_cast<float2*>(out + (size_t)b * N_CLASSES);
    #pragma unroll
    for (int c = 0; c < N_CLASSES / 2; ++c)
        o[c] = make_float2(d[2 * c] - m - lse, d[2 * c + 1] - m - lse);
}

extern "C" void kernel_launch(void* const* d_in, const int* in_sizes, int n_in,
                              void* d_out, int out_size, void* d_ws, size_t ws_size,
                              hipStream_t stream) {
    const float* x          = (const float*)d_in[0];   // [50000,100] f32
    const float* thresholds = (const float*)d_in[1];   // [2000,63]  f32
    const float* leaves     = (const float*)d_in[2];   // [2000,64]  f32
    const int*   features   = (const int*)d_in[3];     // [2000,63]  i32
    // d_in[4] = classes (int64 arange, unused)

    const size_t nodes_bytes    = (size_t)T_TREES * NODE_STRIDE * sizeof(int2);       // 1.0 MB
    const size_t partials_bytes = (size_t)NCHUNK * B_SAMPLES * N_CLASSES * sizeof(float); // 20 MB
    const size_t accum_bytes    = (size_t)B_SAMPLES * N_CLASSES * sizeof(float);      // 2 MB

    int2*  nodes  = (int2*)d_ws;
    float* accbuf = (float*)((char*)d_ws + nodes_bytes);
    const bool use_partials = (ws_size >= nodes_bytes + partials_bytes);

    {
        int total = T_TREES * N_INTERNAL;
        pack_nodes_kernel<<<(total + 255) / 256, 256, 0, stream>>>(thresholds, features, nodes);
    }

    if (use_partials) {
        forest_kernel<true><<<NSB * NCHUNK, BLK, 0, stream>>>(x, nodes, leaves, accbuf);
        softmax_kernel<true><<<(B_SAMPLES + 255) / 256, 256, 0, stream>>>(accbuf, (float*)d_out);
    } else {
        hipMemsetAsync(accbuf, 0, accum_bytes, stream);
        forest_kernel<false><<<NSB * NCHUNK, BLK, 0, stream>>>(x, nodes, leaves, accbuf);
        softmax_kernel<false><<<(B_SAMPLES + 255) / 256, 256, 0, stream>>>(accbuf, (float*)d_out);
    }
}